// Round 1
// baseline (113.425 us; speedup 1.0000x reference)
//
#include <hip/hip_runtime.h>
#include <math.h>

#define DD 256
#define NW 4     // rows (waves) per block
#define MFIX 24  // fixed mode count; with L = range_v+10, omega_24 >= 4.3 always
#define MG 8     // modes per P1/P2 interleave group (3 groups of 8)

typedef float v2f __attribute__((ext_vector_type(2)));
typedef float v4f __attribute__((ext_vector_type(4)));

// ---- DPP wave-64 reduction helpers (no LDS, no barrier) ----
template <int CTRL>
__device__ __forceinline__ float dpp_add(float x) {
    return x + __int_as_float(__builtin_amdgcn_update_dpp(
        0, __float_as_int(x), CTRL, 0xf, 0xf, false));
}
template <int CTRL>
__device__ __forceinline__ float dpp_mov_self(float x) {
    return __int_as_float(__builtin_amdgcn_update_dpp(
        __float_as_int(x), __float_as_int(x), CTRL, 0xf, 0xf, false));
}
// After this chain lane 63 holds the 64-lane total.
__device__ __forceinline__ float wave_sum_chain(float x) {
    x = dpp_add<0x111>(x); x = dpp_add<0x112>(x);
    x = dpp_add<0x114>(x); x = dpp_add<0x118>(x);
    x = dpp_add<0x142>(x); x = dpp_add<0x143>(x);
    return x;
}
__device__ __forceinline__ float lane63(float x) {
    return __int_as_float(__builtin_amdgcn_readlane(__float_as_int(x), 63));
}
__device__ __forceinline__ float wave_max_chain(float x) {
    x = __builtin_fmaxf(x, dpp_mov_self<0x111>(x));
    x = __builtin_fmaxf(x, dpp_mov_self<0x112>(x));
    x = __builtin_fmaxf(x, dpp_mov_self<0x114>(x));
    x = __builtin_fmaxf(x, dpp_mov_self<0x118>(x));
    x = __builtin_fmaxf(x, dpp_mov_self<0x142>(x));
    x = __builtin_fmaxf(x, dpp_mov_self<0x143>(x));
    return x;
}
__device__ __forceinline__ float wave_min_chain(float x) {
    x = __builtin_fminf(x, dpp_mov_self<0x111>(x));
    x = __builtin_fminf(x, dpp_mov_self<0x112>(x));
    x = __builtin_fminf(x, dpp_mov_self<0x114>(x));
    x = __builtin_fminf(x, dpp_mov_self<0x118>(x));
    x = __builtin_fminf(x, dpp_mov_self<0x142>(x));
    x = __builtin_fminf(x, dpp_mov_self<0x143>(x));
    return x;
}

// Giles' erfinv, central branch (|y| <= 1-1/256 => w <= 4.86 < 5), branchless.
__device__ __forceinline__ float ppf_from_y(float y) {
    float omy2 = __builtin_fmaf(-y, y, 1.0f);
    float wg = __builtin_fmaf(-__builtin_amdgcn_logf(omy2), 0.69314718056f, -2.5f);
    float p = 2.81022636e-08f;
    p = __builtin_fmaf(p, wg, 3.43273939e-07f);
    p = __builtin_fmaf(p, wg, -3.5233877e-06f);
    p = __builtin_fmaf(p, wg, -4.39150654e-06f);
    p = __builtin_fmaf(p, wg, 0.00021858087f);
    p = __builtin_fmaf(p, wg, -0.00125372503f);
    p = __builtin_fmaf(p, wg, -0.00417768164f);
    p = __builtin_fmaf(p, wg, 0.246640727f);
    p = __builtin_fmaf(p, wg, 1.50140941f);
    return p * y * 1.41421356237309505f;
}

// Poisson-summation KDE-CDF (validated R6/R7 of prior session), restructured:
//  - Chebyshev 3-term recurrence: sin(m t)=2cos(t)sin((m-1)t)-sin((m-2)t)
//    => 1 FMA per element per trig stream (was mul+fma via angle addition).
//  - gamma_m scale folded into per-lane partials BEFORE reduction, so the
//    readlane results are final wave-uniform coefficients -> SGPR-resident
//    (frees ~48 VGPRs of PC/PS storage for occupancy).
//  - P1/P2 interleaved in groups of MG=8 modes: 16 partials live at a time,
//    16 independent DPP chains per group (latency pipelined).
// Lane l owns elements 4l..4l+3 (float4 coalesced I/O; reductions are
// lane-mapping agnostic).
__global__ __launch_bounds__(64 * NW, 6) void kd_layernorm_kernel(
        const float* __restrict__ x,
        const float* __restrict__ wgt,
        const float* __restrict__ bia,
        float* __restrict__ out) {
    const int lane = threadIdx.x & 63;
    const int wid  = threadIdx.x >> 6;
    const int row  = blockIdx.x * NW + wid;

    const v4f u = ((const v4f*)(x + (size_t)row * DD))[lane];

    float ssum = lane63(wave_sum_chain((u.x + u.y) + (u.z + u.w)));
    float qsum = lane63(wave_sum_chain(__builtin_fmaf(u.x, u.x, u.y * u.y) +
                                       __builtin_fmaf(u.z, u.z, u.w * u.w)));
    float xmax = lane63(wave_max_chain(__builtin_fmaxf(__builtin_fmaxf(u.x, u.y),
                                                       __builtin_fmaxf(u.z, u.w))));
    float xmin = lane63(wave_min_chain(__builtin_fminf(__builtin_fminf(u.x, u.y),
                                                       __builtin_fminf(u.z, u.w))));

    float var = (qsum - ssum * ssum * (1.0f / DD)) * (1.0f / (DD - 1)); // ddof=1
    float bw = 0.9f * __builtin_sqrtf(var) * 0.32987697769322355f;      // *256^-0.2
    float invbw = __builtin_amdgcn_rcpf(bw);
    v4f v = u * invbw;
    float meanv = ssum * invbw * (1.0f / DD);

    float L = (xmax - xmin) * invbw + 10.0f;   // periodization margin 10 sigma_k
    float invL = __builtin_amdgcn_rcpf(L);

    // v_sin/v_cos take revolutions; angle_1 = v/L revolutions (verified R7).
    v4f ph = v * invL;
    v4f s1, c1;
    s1.x = __builtin_amdgcn_sinf(ph.x); s1.y = __builtin_amdgcn_sinf(ph.y);
    s1.z = __builtin_amdgcn_sinf(ph.z); s1.w = __builtin_amdgcn_sinf(ph.w);
    c1.x = __builtin_amdgcn_cosf(ph.x); c1.y = __builtin_amdgcn_cosf(ph.y);
    c1.z = __builtin_amdgcn_cosf(ph.z); c1.w = __builtin_amdgcn_cosf(ph.w);
    v4f twoC = c1 + c1;   // Chebyshev multiplier 2*cos(theta)

    // gamma_m = e^{-m^2 w1^2 / 2} via multiplicative recurrence (exp2 folded).
    float w1sq = 39.4784176044f * invL * invL;  // (2pi/L)^2
    float g    = __builtin_amdgcn_exp2f(-0.72134752f * w1sq);
    float rr   = __builtin_amdgcn_exp2f(-2.16404256f * w1sq);
    const float rho = __builtin_amdgcn_exp2f(-1.44269504f * w1sq);

    // Final wave-uniform coefficients (SGPR-resident: produced by readlane).
    // Scale folded: sc_m = gamma_m / (128*pi*(m+1))  [includes the epilogue's
    // 2/256 factor]; gS stored pre-negated so P3 is a plain FMA.
    float gC[MFIX], gS[MFIX];
    {
        v4f sm = s1, cm = c1;                       // mode 1
        v4f sm1 = {0.f, 0.f, 0.f, 0.f};             // mode 0: sin=0
        v4f cm1 = {1.f, 1.f, 1.f, 1.f};             // mode 0: cos=1
        #pragma unroll
        for (int grp = 0; grp < MFIX / MG; ++grp) {
            float pc[MG], ps[MG];
            #pragma unroll
            for (int k = 0; k < MG; ++k) {
                const int m = grp * MG + k;
                float sc = g * (0.0024867959f / (float)(m + 1)); // 1/(128*pi*(m+1))
                pc[k] = ((cm.x + cm.y) + (cm.z + cm.w)) * sc;
                ps[k] = ((sm.x + sm.y) + (sm.z + sm.w)) * (-sc);
                g *= rr; rr *= rho;
                v4f sn = __builtin_elementwise_fma(twoC, sm, -sm1);
                v4f cn = __builtin_elementwise_fma(twoC, cm, -cm1);
                sm1 = sm; sm = sn;
                cm1 = cm; cm = cn;
            }
            // 2*MG independent DPP chains: pipelined, then readlane -> SGPR.
            #pragma unroll
            for (int k = 0; k < MG; ++k) {
                const int m = grp * MG + k;
                gC[m] = lane63(wave_sum_chain(pc[k]));
                gS[m] = lane63(wave_sum_chain(ps[k]));
            }
        }
    }

    // Hoist scale/shift loads: latency hidden under the P3 mode loop.
    const v4f wv = ((const v4f*)wgt)[lane];
    const v4f bv = ((const v4f*)bia)[lane];

    // ---- P3: R_j = sum_m gC_m sin(m t_j) + gS_m cos(m t_j) (gS pre-negated)
    v4f R = {0.f, 0.f, 0.f, 0.f};
    {
        v4f sm = s1, cm = c1;
        v4f sm1 = {0.f, 0.f, 0.f, 0.f};
        v4f cm1 = {1.f, 1.f, 1.f, 1.f};
        #pragma unroll
        for (int m = 0; m < MFIX; ++m) {
            R.x = __builtin_fmaf(sm.x, gC[m], R.x);
            R.y = __builtin_fmaf(sm.y, gC[m], R.y);
            R.z = __builtin_fmaf(sm.z, gC[m], R.z);
            R.w = __builtin_fmaf(sm.w, gC[m], R.w);
            R.x = __builtin_fmaf(cm.x, gS[m], R.x);
            R.y = __builtin_fmaf(cm.y, gS[m], R.y);
            R.z = __builtin_fmaf(cm.z, gS[m], R.z);
            R.w = __builtin_fmaf(cm.w, gS[m], R.w);
            v4f sn = __builtin_elementwise_fma(twoC, sm, -sm1);
            v4f cn = __builtin_elementwise_fma(twoC, cm, -cm1);
            sm1 = sm; sm = sn;
            cm1 = cm; cm = cn;
        }
    }

    // ---- Epilogue: y = (v-meanv)*2/L + R  (2/256 already folded into R)
    const float t2iL = invL + invL;
    v4f o;
    o.x = __builtin_fmaf(ppf_from_y(__builtin_fmaf(v.x - meanv, t2iL, R.x)), wv.x, bv.x);
    o.y = __builtin_fmaf(ppf_from_y(__builtin_fmaf(v.y - meanv, t2iL, R.y)), wv.y, bv.y);
    o.z = __builtin_fmaf(ppf_from_y(__builtin_fmaf(v.z - meanv, t2iL, R.z)), wv.z, bv.z);
    o.w = __builtin_fmaf(ppf_from_y(__builtin_fmaf(v.w - meanv, t2iL, R.w)), wv.w, bv.w);
    ((v4f*)(out + (size_t)row * DD))[lane] = o;
}

extern "C" void kernel_launch(void* const* d_in, const int* in_sizes, int n_in,
                              void* d_out, int out_size, void* d_ws, size_t ws_size,
                              hipStream_t stream) {
    const float* x = (const float*)d_in[0];
    const float* w = (const float*)d_in[1];
    const float* b = (const float*)d_in[2];
    float* out = (float*)d_out;
    const int nrows = in_sizes[0] / DD;
    kd_layernorm_kernel<<<nrows / NW, 64 * NW, 0, stream>>>(x, w, b, out);
}

// Round 2
// 108.430 us; speedup vs baseline: 1.0461x; 1.0461x over previous
//
#include <hip/hip_runtime.h>
#include <math.h>

#define DD 256
#define NW 4     // rows (waves) per block
#define MFIX 24  // fixed mode count; with L = range_v+10, omega_24 >= 4.3 always
#define MG 8     // modes per pipeline group (3 groups of 8)

typedef float v2f __attribute__((ext_vector_type(2)));
typedef float v4f __attribute__((ext_vector_type(4)));

// ---- DPP wave-64 reduction helpers (no LDS, no barrier) ----
template <int CTRL>
__device__ __forceinline__ float dpp_add(float x) {
    return x + __int_as_float(__builtin_amdgcn_update_dpp(
        0, __float_as_int(x), CTRL, 0xf, 0xf, false));
}
template <int CTRL>
__device__ __forceinline__ float dpp_mov_self(float x) {
    return __int_as_float(__builtin_amdgcn_update_dpp(
        __float_as_int(x), __float_as_int(x), CTRL, 0xf, 0xf, false));
}
// After this chain lane 63 holds the 64-lane total.
__device__ __forceinline__ float wave_sum_chain(float x) {
    x = dpp_add<0x111>(x); x = dpp_add<0x112>(x);
    x = dpp_add<0x114>(x); x = dpp_add<0x118>(x);
    x = dpp_add<0x142>(x); x = dpp_add<0x143>(x);
    return x;
}
__device__ __forceinline__ float lane63(float x) {
    return __int_as_float(__builtin_amdgcn_readlane(__float_as_int(x), 63));
}
__device__ __forceinline__ float wave_max_chain(float x) {
    x = __builtin_fmaxf(x, dpp_mov_self<0x111>(x));
    x = __builtin_fmaxf(x, dpp_mov_self<0x112>(x));
    x = __builtin_fmaxf(x, dpp_mov_self<0x114>(x));
    x = __builtin_fmaxf(x, dpp_mov_self<0x118>(x));
    x = __builtin_fmaxf(x, dpp_mov_self<0x142>(x));
    x = __builtin_fmaxf(x, dpp_mov_self<0x143>(x));
    return x;
}
__device__ __forceinline__ float wave_min_chain(float x) {
    x = __builtin_fminf(x, dpp_mov_self<0x111>(x));
    x = __builtin_fminf(x, dpp_mov_self<0x112>(x));
    x = __builtin_fminf(x, dpp_mov_self<0x114>(x));
    x = __builtin_fminf(x, dpp_mov_self<0x118>(x));
    x = __builtin_fminf(x, dpp_mov_self<0x142>(x));
    x = __builtin_fminf(x, dpp_mov_self<0x143>(x));
    return x;
}

// Giles' erfinv, central branch (|y| <= 1-1/256 => w <= 4.86 < 5), branchless.
__device__ __forceinline__ float ppf_from_y(float y) {
    float omy2 = __builtin_fmaf(-y, y, 1.0f);
    float wg = __builtin_fmaf(-__builtin_amdgcn_logf(omy2), 0.69314718056f, -2.5f);
    float p = 2.81022636e-08f;
    p = __builtin_fmaf(p, wg, 3.43273939e-07f);
    p = __builtin_fmaf(p, wg, -3.5233877e-06f);
    p = __builtin_fmaf(p, wg, -4.39150654e-06f);
    p = __builtin_fmaf(p, wg, 0.00021858087f);
    p = __builtin_fmaf(p, wg, -0.00125372503f);
    p = __builtin_fmaf(p, wg, -0.00417768164f);
    p = __builtin_fmaf(p, wg, 0.246640727f);
    p = __builtin_fmaf(p, wg, 1.50140941f);
    return p * y * 1.41421356237309505f;
}

// P1: scaled Fourier partials for one mode from state A, advance A (Chebyshev).
// Scale folded: sc_m = gamma_m / (128*pi*m)  [includes epilogue's 2/256].
#define P1_ADV(MODE, K) do {                                                  \
    const float sc_ = g * (0.0024867959f / (float)(MODE));                    \
    pc[K] = ((cA.x + cA.y) + (cA.z + cA.w)) * sc_;                            \
    ps[K] = ((sA.x + sA.y) + (sA.z + sA.w)) * sc_;                            \
    g *= rr; rr *= rho;                                                       \
    v4f sn_ = __builtin_elementwise_fma(twoC, sA, -sA1);                      \
    v4f cn_ = __builtin_elementwise_fma(twoC, cA, -cA1);                      \
    sA1 = sA; sA = sn_; cA1 = cA; cA = cn_;                                   \
} while (0)

// P3: R += coefC*sin(m t) - coefS*cos(m t) from state B, advance B.
// Split accumulators halve the serial accumulation chain.
#define P3_ADV(K) do {                                                        \
    R0.x = __builtin_fmaf(sB.x, coefC[K], R0.x);                              \
    R0.y = __builtin_fmaf(sB.y, coefC[K], R0.y);                              \
    R0.z = __builtin_fmaf(sB.z, coefC[K], R0.z);                              \
    R0.w = __builtin_fmaf(sB.w, coefC[K], R0.w);                              \
    R1.x = __builtin_fmaf(cB.x, -coefS[K], R1.x);                             \
    R1.y = __builtin_fmaf(cB.y, -coefS[K], R1.y);                             \
    R1.z = __builtin_fmaf(cB.z, -coefS[K], R1.z);                             \
    R1.w = __builtin_fmaf(cB.w, -coefS[K], R1.w);                             \
    v4f sn_ = __builtin_elementwise_fma(twoC, sB, -sB1);                      \
    v4f cn_ = __builtin_elementwise_fma(twoC, cB, -cB1);                      \
    sB1 = sB; sB = sn_; cB1 = cB; cB = cn_;                                   \
} while (0)

// 2*MG independent DPP reduction chains -> wave-uniform coeffs (SGPR via readlane)
#define REDUCE_GRP() do {                                                     \
    _Pragma("unroll")                                                         \
    for (int k_ = 0; k_ < MG; ++k_) {                                         \
        coefC[k_] = lane63(wave_sum_chain(pc[k_]));                           \
        coefS[k_] = lane63(wave_sum_chain(ps[k_]));                           \
    }                                                                         \
} while (0)

// Poisson-summation KDE-CDF, group-pipelined:
//   group g:   P1(A-state) computes 16 scaled partials
//   lag 1:     P3(B-state) consumes group g-1's 16 wave-uniform coefficients
// Only 16 coefficients + 16 partials live at any time (vs 48 in the spilled
// R1 version); states A,B are independent Chebyshev recurrences -> ILP.
__global__ __launch_bounds__(64 * NW, 5) void kd_layernorm_kernel(
        const float* __restrict__ x,
        const float* __restrict__ wgt,
        const float* __restrict__ bia,
        float* __restrict__ out) {
    const int lane = threadIdx.x & 63;
    const int wid  = threadIdx.x >> 6;
    const int row  = blockIdx.x * NW + wid;

    const v4f u = ((const v4f*)(x + (size_t)row * DD))[lane];

    float ssum = lane63(wave_sum_chain((u.x + u.y) + (u.z + u.w)));
    float qsum = lane63(wave_sum_chain(__builtin_fmaf(u.x, u.x, u.y * u.y) +
                                       __builtin_fmaf(u.z, u.z, u.w * u.w)));
    float xmax = lane63(wave_max_chain(__builtin_fmaxf(__builtin_fmaxf(u.x, u.y),
                                                       __builtin_fmaxf(u.z, u.w))));
    float xmin = lane63(wave_min_chain(__builtin_fminf(__builtin_fminf(u.x, u.y),
                                                       __builtin_fminf(u.z, u.w))));

    float var = (qsum - ssum * ssum * (1.0f / DD)) * (1.0f / (DD - 1)); // ddof=1
    float bw = 0.9f * __builtin_sqrtf(var) * 0.32987697769322355f;      // *256^-0.2
    float invbw = __builtin_amdgcn_rcpf(bw);
    v4f v = u * invbw;
    float meanv = ssum * invbw * (1.0f / DD);

    float L = (xmax - xmin) * invbw + 10.0f;   // periodization margin 10 sigma_k
    float invL = __builtin_amdgcn_rcpf(L);

    // v_sin/v_cos take revolutions; angle_1 = v/L revolutions (verified R7).
    v4f ph = v * invL;
    v4f s1, c1;
    s1.x = __builtin_amdgcn_sinf(ph.x); s1.y = __builtin_amdgcn_sinf(ph.y);
    s1.z = __builtin_amdgcn_sinf(ph.z); s1.w = __builtin_amdgcn_sinf(ph.w);
    c1.x = __builtin_amdgcn_cosf(ph.x); c1.y = __builtin_amdgcn_cosf(ph.y);
    c1.z = __builtin_amdgcn_cosf(ph.z); c1.w = __builtin_amdgcn_cosf(ph.w);
    v4f twoC = c1 + c1;   // Chebyshev multiplier 2*cos(theta)

    // gamma_m = e^{-m^2 w1^2 / 2} via multiplicative recurrence (exp2 folded).
    float w1sq = 39.4784176044f * invL * invL;  // (2pi/L)^2
    float g    = __builtin_amdgcn_exp2f(-0.72134752f * w1sq);
    float rr   = __builtin_amdgcn_exp2f(-2.16404256f * w1sq);
    const float rho = __builtin_amdgcn_exp2f(-1.44269504f * w1sq);

    float pc[MG], ps[MG];        // per-lane scaled partials (VGPR)
    float coefC[MG], coefS[MG];  // wave-uniform reduced coeffs (SGPR via readlane)
    v4f sA = s1, cA = c1; v4f sA1 = {0.f, 0.f, 0.f, 0.f}, cA1 = {1.f, 1.f, 1.f, 1.f};
    v4f sB = s1, cB = c1; v4f sB1 = {0.f, 0.f, 0.f, 0.f}, cB1 = {1.f, 1.f, 1.f, 1.f};
    v4f R0 = {0.f, 0.f, 0.f, 0.f}, R1 = {0.f, 0.f, 0.f, 0.f};

    // Prologue: group 0 partials + reduction.
    #pragma unroll
    for (int k = 0; k < MG; ++k) P1_ADV(k + 1, k);
    REDUCE_GRP();

    // Pipelined groups: P1(grp) || P3(grp-1), then reduce grp.
    #pragma unroll
    for (int grp = 1; grp < MFIX / MG; ++grp) {
        #pragma unroll
        for (int k = 0; k < MG; ++k) P1_ADV(grp * MG + k + 1, k);
        #pragma unroll
        for (int k = 0; k < MG; ++k) P3_ADV(k);
        REDUCE_GRP();
    }

    // Scale/shift loads issued before the tail so latency hides under P3.
    const v4f wv = ((const v4f*)wgt)[lane];
    const v4f bv = ((const v4f*)bia)[lane];

    // Epilogue group: P3(last).
    #pragma unroll
    for (int k = 0; k < MG; ++k) P3_ADV(k);

    v4f R = R0 + R1;

    // ---- Epilogue: y = (v-meanv)*2/L + R  (2/256 already folded into R)
    const float t2iL = invL + invL;
    v4f o;
    o.x = __builtin_fmaf(ppf_from_y(__builtin_fmaf(v.x - meanv, t2iL, R.x)), wv.x, bv.x);
    o.y = __builtin_fmaf(ppf_from_y(__builtin_fmaf(v.y - meanv, t2iL, R.y)), wv.y, bv.y);
    o.z = __builtin_fmaf(ppf_from_y(__builtin_fmaf(v.z - meanv, t2iL, R.z)), wv.z, bv.z);
    o.w = __builtin_fmaf(ppf_from_y(__builtin_fmaf(v.w - meanv, t2iL, R.w)), wv.w, bv.w);
    ((v4f*)(out + (size_t)row * DD))[lane] = o;
}

extern "C" void kernel_launch(void* const* d_in, const int* in_sizes, int n_in,
                              void* d_out, int out_size, void* d_ws, size_t ws_size,
                              hipStream_t stream) {
    const float* x = (const float*)d_in[0];
    const float* w = (const float*)d_in[1];
    const float* b = (const float*)d_in[2];
    float* out = (float*)d_out;
    const int nrows = in_sizes[0] / DD;
    kd_layernorm_kernel<<<nrows / NW, 64 * NW, 0, stream>>>(x, w, b, out);
}

// Round 3
// 78.119 us; speedup vs baseline: 1.4520x; 1.3880x over previous
//
#include <hip/hip_runtime.h>
#include <math.h>

#define DD 256
#define RPB 2     // rows per block; 2 waves per row (half-row each, 2 elems/lane)
#define MFIX 24   // fixed mode count; with L = range_v+10, omega_24 >= 4.3 always
#define MG 8      // modes per pipeline group (3 groups of 8)
#define NGRP (MFIX / MG)

typedef float v2f __attribute__((ext_vector_type(2)));

// ---- DPP wave-64 reduction helpers (no LDS, no barrier) ----
template <int CTRL>
__device__ __forceinline__ float dpp_add(float x) {
    return x + __int_as_float(__builtin_amdgcn_update_dpp(
        0, __float_as_int(x), CTRL, 0xf, 0xf, false));
}
template <int CTRL>
__device__ __forceinline__ float dpp_mov_self(float x) {
    return __int_as_float(__builtin_amdgcn_update_dpp(
        __float_as_int(x), __float_as_int(x), CTRL, 0xf, 0xf, false));
}
// After this chain lane 63 holds the 64-lane total (other lanes partial).
__device__ __forceinline__ float wave_sum_chain(float x) {
    x = dpp_add<0x111>(x); x = dpp_add<0x112>(x);
    x = dpp_add<0x114>(x); x = dpp_add<0x118>(x);
    x = dpp_add<0x142>(x); x = dpp_add<0x143>(x);
    return x;
}
__device__ __forceinline__ float wave_max_chain(float x) {
    x = __builtin_fmaxf(x, dpp_mov_self<0x111>(x));
    x = __builtin_fmaxf(x, dpp_mov_self<0x112>(x));
    x = __builtin_fmaxf(x, dpp_mov_self<0x114>(x));
    x = __builtin_fmaxf(x, dpp_mov_self<0x118>(x));
    x = __builtin_fmaxf(x, dpp_mov_self<0x142>(x));
    x = __builtin_fmaxf(x, dpp_mov_self<0x143>(x));
    return x;
}
__device__ __forceinline__ float wave_min_chain(float x) {
    x = __builtin_fminf(x, dpp_mov_self<0x111>(x));
    x = __builtin_fminf(x, dpp_mov_self<0x112>(x));
    x = __builtin_fminf(x, dpp_mov_self<0x114>(x));
    x = __builtin_fminf(x, dpp_mov_self<0x118>(x));
    x = __builtin_fminf(x, dpp_mov_self<0x142>(x));
    x = __builtin_fminf(x, dpp_mov_self<0x143>(x));
    return x;
}
__device__ __forceinline__ float rfl(float x) {
    return __int_as_float(__builtin_amdgcn_readfirstlane(__float_as_int(x)));
}

// Giles' erfinv, central branch (|y| <= 1-1/256 => w <= 4.86 < 5), branchless.
__device__ __forceinline__ float ppf_from_y(float y) {
    float omy2 = __builtin_fmaf(-y, y, 1.0f);
    float wg = __builtin_fmaf(-__builtin_amdgcn_logf(omy2), 0.69314718056f, -2.5f);
    float p = 2.81022636e-08f;
    p = __builtin_fmaf(p, wg, 3.43273939e-07f);
    p = __builtin_fmaf(p, wg, -3.5233877e-06f);
    p = __builtin_fmaf(p, wg, -4.39150654e-06f);
    p = __builtin_fmaf(p, wg, 0.00021858087f);
    p = __builtin_fmaf(p, wg, -0.00125372503f);
    p = __builtin_fmaf(p, wg, -0.00417768164f);
    p = __builtin_fmaf(p, wg, 0.246640727f);
    p = __builtin_fmaf(p, wg, 1.50140941f);
    return p * y * 1.41421356237309505f;
}

// P1: scaled Fourier partials for one mode from state A; DPP-chain them
// (total lands in lane 63); advance A via Chebyshev 3-term recurrence.
// Scale folded: sc_m = gamma_m / (128*pi*m)  [includes epilogue's 2/256];
// sine partial pre-negated so P3 and the combine are plain adds/FMAs.
#define P1_ADV(MODE, K) do {                                                  \
    const float sc_ = g * (0.0024867959f / (float)(MODE));                    \
    tC[K] = wave_sum_chain((cA.x + cA.y) * sc_);                              \
    tS[K] = wave_sum_chain((sA.x + sA.y) * (-sc_));                           \
    g *= rr; rr *= rho;                                                       \
    v2f sn_ = __builtin_elementwise_fma(twoC, sA, -sA1);                      \
    v2f cn_ = __builtin_elementwise_fma(twoC, cA, -cA1);                      \
    sA1 = sA; sA = sn_; cA1 = cA; cA = cn_;                                   \
} while (0)

// Lane 63 publishes this wave's 16 half-row sums for group G, then barrier.
#define WRITE_GRP(G) do {                                                     \
    if (lane == 63) {                                                         \
        _Pragma("unroll")                                                     \
        for (int k_ = 0; k_ < MG; ++k_) {                                     \
            gcoef[G][wid][k_]      = tC[k_];                                  \
            gcoef[G][wid][MG + k_] = tS[k_];                                  \
        }                                                                     \
    }                                                                         \
    __syncthreads();                                                          \
} while (0)

// Combine the two half-row sums (same order in both waves -> bit-identical),
// pin to SGPR via readfirstlane.
#define COMBINE_GRP(G) do {                                                   \
    _Pragma("unroll")                                                         \
    for (int k_ = 0; k_ < MG; ++k_) {                                         \
        coefC[k_] = rfl(gcoef[G][rbase][k_]      + gcoef[G][rbase | 1][k_]);  \
        coefS[k_] = rfl(gcoef[G][rbase][MG + k_] + gcoef[G][rbase | 1][MG + k_]); \
    }                                                                         \
} while (0)

// P3: R += coefC*sin(m t) + coefS*cos(m t) (coefS pre-negated) from state B.
#define P3_ADV(K) do {                                                        \
    R0.x = __builtin_fmaf(sB.x, coefC[K], R0.x);                              \
    R0.y = __builtin_fmaf(sB.y, coefC[K], R0.y);                              \
    R1.x = __builtin_fmaf(cB.x, coefS[K], R1.x);                              \
    R1.y = __builtin_fmaf(cB.y, coefS[K], R1.y);                              \
    v2f sn_ = __builtin_elementwise_fma(twoC, sB, -sB1);                      \
    v2f cn_ = __builtin_elementwise_fma(twoC, cB, -cB1);                      \
    sB1 = sB; sB = sn_; cB1 = cB; cB = cn_;                                   \
} while (0)

// Poisson-summation KDE-CDF, 2 waves per row (2 elems/lane, v2 state):
//  - doubles wave count (8192) -> 8 waves/SIMD available (was grid-capped at 4)
//  - halves per-wave register state -> no launch_bounds forcing, no spill
//  - group-pipelined: P1(A-state, grp) || P3(B-state, grp-1), LDS combine
__global__ __launch_bounds__(256) void kd_layernorm_kernel(
        const float* __restrict__ x,
        const float* __restrict__ wgt,
        const float* __restrict__ bia,
        float* __restrict__ out) {
    const int lane  = threadIdx.x & 63;
    const int wid   = threadIdx.x >> 6;   // 0..3
    const int half  = wid & 1;            // which half-row this wave owns
    const int rbase = wid & 2;            // partner-pair base wave id
    const int row   = blockIdx.x * RPB + (wid >> 1);

    __shared__ float sred[4][4];              // per-wave {sum,sq,max,min}
    __shared__ float gcoef[NGRP][4][2 * MG];  // per-group half-row Fourier sums

    const float* xr = x + (size_t)row * DD + (half << 7);
    const v2f u = ((const v2f*)xr)[lane];

    // Half-row stats (totals end in lane 63), publish, combine across halves.
    {
        float a = wave_sum_chain(u.x + u.y);
        float b = wave_sum_chain(__builtin_fmaf(u.x, u.x, u.y * u.y));
        float c = wave_max_chain(__builtin_fmaxf(u.x, u.y));
        float d = wave_min_chain(__builtin_fminf(u.x, u.y));
        if (lane == 63) {
            sred[wid][0] = a; sred[wid][1] = b; sred[wid][2] = c; sred[wid][3] = d;
        }
    }
    __syncthreads();
    float ssum = sred[rbase][0] + sred[rbase | 1][0];
    float qsum = sred[rbase][1] + sred[rbase | 1][1];
    float xmax = __builtin_fmaxf(sred[rbase][2], sred[rbase | 1][2]);
    float xmin = __builtin_fminf(sred[rbase][3], sred[rbase | 1][3]);

    float var = (qsum - ssum * ssum * (1.0f / DD)) * (1.0f / (DD - 1)); // ddof=1
    float bw = 0.9f * __builtin_sqrtf(var) * 0.32987697769322355f;      // *256^-0.2
    float invbw = __builtin_amdgcn_rcpf(bw);
    v2f v = u * invbw;
    float meanv = ssum * invbw * (1.0f / DD);

    float L = (xmax - xmin) * invbw + 10.0f;   // periodization margin 10 sigma_k
    float invL = __builtin_amdgcn_rcpf(L);

    // v_sin/v_cos take revolutions; angle_1 = v/L revolutions (verified R7).
    v2f ph = v * invL;
    v2f s1, c1;
    s1.x = __builtin_amdgcn_sinf(ph.x); s1.y = __builtin_amdgcn_sinf(ph.y);
    c1.x = __builtin_amdgcn_cosf(ph.x); c1.y = __builtin_amdgcn_cosf(ph.y);
    v2f twoC = c1 + c1;   // Chebyshev multiplier 2*cos(theta)

    // gamma_m = e^{-m^2 w1^2 / 2} via multiplicative recurrence (exp2 folded).
    float w1sq = 39.4784176044f * invL * invL;  // (2pi/L)^2
    float g    = __builtin_amdgcn_exp2f(-0.72134752f * w1sq);
    float rr   = __builtin_amdgcn_exp2f(-2.16404256f * w1sq);
    const float rho = __builtin_amdgcn_exp2f(-1.44269504f * w1sq);

    float tC[MG], tS[MG];        // transient: this group's chained sums
    float coefC[MG], coefS[MG];  // wave-uniform coefficients (SGPR via rfl)
    v2f sA = s1, cA = c1; v2f sA1 = {0.f, 0.f}, cA1 = {1.f, 1.f};
    v2f sB = s1, cB = c1; v2f sB1 = {0.f, 0.f}, cB1 = {1.f, 1.f};
    v2f R0 = {0.f, 0.f}, R1 = {0.f, 0.f};

    // Prologue: group 0 partials.
    #pragma unroll
    for (int k = 0; k < MG; ++k) P1_ADV(k + 1, k);
    WRITE_GRP(0);

    // Pipelined: combine(g-1); P1(g) || P3(g-1); publish g.
    COMBINE_GRP(0);
    #pragma unroll
    for (int k = 0; k < MG; ++k) P1_ADV(MG + k + 1, k);
    #pragma unroll
    for (int k = 0; k < MG; ++k) P3_ADV(k);
    WRITE_GRP(1);

    COMBINE_GRP(1);
    #pragma unroll
    for (int k = 0; k < MG; ++k) P1_ADV(2 * MG + k + 1, k);
    #pragma unroll
    for (int k = 0; k < MG; ++k) P3_ADV(k);
    WRITE_GRP(2);

    // Scale/shift loads issued early: latency hidden under the tail group.
    const v2f wv = ((const v2f*)wgt)[(half << 6) + lane];
    const v2f bv = ((const v2f*)bia)[(half << 6) + lane];

    COMBINE_GRP(2);
    #pragma unroll
    for (int k = 0; k < MG; ++k) P3_ADV(k);

    v2f R = R0 + R1;

    // ---- Epilogue: y = (v-meanv)*2/L + R  (2/256 already folded into R)
    const float t2iL = invL + invL;
    v2f o;
    o.x = __builtin_fmaf(ppf_from_y(__builtin_fmaf(v.x - meanv, t2iL, R.x)), wv.x, bv.x);
    o.y = __builtin_fmaf(ppf_from_y(__builtin_fmaf(v.y - meanv, t2iL, R.y)), wv.y, bv.y);
    ((v2f*)(out + (size_t)row * DD + (half << 7)))[lane] = o;
}

extern "C" void kernel_launch(void* const* d_in, const int* in_sizes, int n_in,
                              void* d_out, int out_size, void* d_ws, size_t ws_size,
                              hipStream_t stream) {
    const float* x = (const float*)d_in[0];
    const float* w = (const float*)d_in[1];
    const float* b = (const float*)d_in[2];
    float* out = (float*)d_out;
    const int nrows = in_sizes[0] / DD;
    kd_layernorm_kernel<<<nrows / RPB, 256, 0, stream>>>(x, w, b, out);
}

// Round 4
// 67.576 us; speedup vs baseline: 1.6785x; 1.1560x over previous
//
#include <hip/hip_runtime.h>
#include <math.h>

#define DD 256
#define NW 4     // rows (waves) per block, 1 wave per row, 4 elems/lane
#define MFIX 24  // fixed mode count; with L = range_v+10, omega_24 >= 4.3 always
#define MG 8     // modes per pipeline group (3 groups of 8)

typedef float v4f __attribute__((ext_vector_type(4)));

// ---- DPP wave-64 reduction helpers (no LDS, no barrier) ----
template <int CTRL>
__device__ __forceinline__ float dpp_add(float x) {
    return x + __int_as_float(__builtin_amdgcn_update_dpp(
        0, __float_as_int(x), CTRL, 0xf, 0xf, false));
}
template <int CTRL>
__device__ __forceinline__ float dpp_mov_self(float x) {
    return __int_as_float(__builtin_amdgcn_update_dpp(
        __float_as_int(x), __float_as_int(x), CTRL, 0xf, 0xf, false));
}
// After this chain lane 63 holds the 64-lane total (other lanes partial).
__device__ __forceinline__ float wave_sum_chain(float x) {
    x = dpp_add<0x111>(x); x = dpp_add<0x112>(x);
    x = dpp_add<0x114>(x); x = dpp_add<0x118>(x);
    x = dpp_add<0x142>(x); x = dpp_add<0x143>(x);
    return x;
}
__device__ __forceinline__ float lane63(float x) {
    return __int_as_float(__builtin_amdgcn_readlane(__float_as_int(x), 63));
}
__device__ __forceinline__ float wave_max_chain(float x) {
    x = __builtin_fmaxf(x, dpp_mov_self<0x111>(x));
    x = __builtin_fmaxf(x, dpp_mov_self<0x112>(x));
    x = __builtin_fmaxf(x, dpp_mov_self<0x114>(x));
    x = __builtin_fmaxf(x, dpp_mov_self<0x118>(x));
    x = __builtin_fmaxf(x, dpp_mov_self<0x142>(x));
    x = __builtin_fmaxf(x, dpp_mov_self<0x143>(x));
    return x;
}
__device__ __forceinline__ float wave_min_chain(float x) {
    x = __builtin_fminf(x, dpp_mov_self<0x111>(x));
    x = __builtin_fminf(x, dpp_mov_self<0x112>(x));
    x = __builtin_fminf(x, dpp_mov_self<0x114>(x));
    x = __builtin_fminf(x, dpp_mov_self<0x118>(x));
    x = __builtin_fminf(x, dpp_mov_self<0x142>(x));
    x = __builtin_fminf(x, dpp_mov_self<0x143>(x));
    return x;
}

// Giles' erfinv, central branch (|y| <= 1-1/256 => w <= 4.86 < 5), branchless.
__device__ __forceinline__ float ppf_from_y(float y) {
    float omy2 = __builtin_fmaf(-y, y, 1.0f);
    float wg = __builtin_fmaf(-__builtin_amdgcn_logf(omy2), 0.69314718056f, -2.5f);
    float p = 2.81022636e-08f;
    p = __builtin_fmaf(p, wg, 3.43273939e-07f);
    p = __builtin_fmaf(p, wg, -3.5233877e-06f);
    p = __builtin_fmaf(p, wg, -4.39150654e-06f);
    p = __builtin_fmaf(p, wg, 0.00021858087f);
    p = __builtin_fmaf(p, wg, -0.00125372503f);
    p = __builtin_fmaf(p, wg, -0.00417768164f);
    p = __builtin_fmaf(p, wg, 0.246640727f);
    p = __builtin_fmaf(p, wg, 1.50140941f);
    return p * y * 1.41421356237309505f;
}

// P1: scaled Fourier partials for one mode from state A, advance A (Chebyshev
// 3-term: x_{m+1} = 2cos(t)*x_m - x_{m-1}, one FMA per element per stream).
// Scale folded: sc_m = gamma_m / (128*pi*m) [includes epilogue's 2/256];
// sine partial pre-negated so P3 is a plain FMA.
#define P1_ADV(MODE, K) do {                                                  \
    const float sc_ = g * (0.0024867959f / (float)(MODE));                    \
    pc[K] = ((cA.x + cA.y) + (cA.z + cA.w)) * sc_;                            \
    ps[K] = ((sA.x + sA.y) + (sA.z + sA.w)) * (-sc_);                         \
    g *= rr; rr *= rho;                                                       \
    v4f sn_ = __builtin_elementwise_fma(twoC, sA, -sA1);                      \
    v4f cn_ = __builtin_elementwise_fma(twoC, cA, -cA1);                      \
    sA1 = sA; sA = sn_; cA1 = cA; cA = cn_;                                   \
} while (0)

// P3: R += coefC*sin(m t) + coefS*cos(m t) (coefS pre-negated), advance B.
// Split accumulators halve the serial accumulation chain.
#define P3_ADV(K) do {                                                        \
    R0.x = __builtin_fmaf(sB.x, coefC[K], R0.x);                              \
    R0.y = __builtin_fmaf(sB.y, coefC[K], R0.y);                              \
    R0.z = __builtin_fmaf(sB.z, coefC[K], R0.z);                              \
    R0.w = __builtin_fmaf(sB.w, coefC[K], R0.w);                              \
    R1.x = __builtin_fmaf(cB.x, coefS[K], R1.x);                              \
    R1.y = __builtin_fmaf(cB.y, coefS[K], R1.y);                              \
    R1.z = __builtin_fmaf(cB.z, coefS[K], R1.z);                              \
    R1.w = __builtin_fmaf(cB.w, coefS[K], R1.w);                              \
    v4f sn_ = __builtin_elementwise_fma(twoC, sB, -sB1);                      \
    v4f cn_ = __builtin_elementwise_fma(twoC, cB, -cB1);                      \
    sB1 = sB; sB = sn_; cB1 = cB; cB = cn_;                                   \
} while (0)

// 2*MG independent DPP reduction chains -> wave-uniform coeffs; readlane
// pins them to SGPRs (saves VGPRs; VALU reads 1 SGPR operand for free).
#define REDUCE_GRP() do {                                                     \
    _Pragma("unroll")                                                         \
    for (int k_ = 0; k_ < MG; ++k_) {                                         \
        coefC[k_] = lane63(wave_sum_chain(pc[k_]));                           \
        coefS[k_] = lane63(wave_sum_chain(ps[k_]));                           \
    }                                                                         \
} while (0)

// Poisson-summation KDE-CDF, group-pipelined, 1 wave per row (no LDS/barriers):
//   group g: P1(A-state) jammed with P3(B-state, consuming group g-1's coeffs)
//   then 16 independent DPP reduction chains for group g.
// Only 16 partials + 16 SGPR coefficients live at a time (R1/R2's spill came
// from the launch_bounds min-waves arg strangling the allocator -- cap was
// ~256/min_waves VGPRs. NO second arg here; natural allocation ~90 VGPR.)
__global__ __launch_bounds__(64 * NW) void kd_layernorm_kernel(
        const float* __restrict__ x,
        const float* __restrict__ wgt,
        const float* __restrict__ bia,
        float* __restrict__ out) {
    const int lane = threadIdx.x & 63;
    const int wid  = threadIdx.x >> 6;
    const int row  = blockIdx.x * NW + wid;

    const v4f u = ((const v4f*)(x + (size_t)row * DD))[lane];
    // weight/bias: tiny, L2-resident; issue early, consumed only in epilogue.
    const v4f wv = ((const v4f*)wgt)[lane];
    const v4f bv = ((const v4f*)bia)[lane];

    float ssum = lane63(wave_sum_chain((u.x + u.y) + (u.z + u.w)));
    float qsum = lane63(wave_sum_chain(__builtin_fmaf(u.x, u.x, u.y * u.y) +
                                       __builtin_fmaf(u.z, u.z, u.w * u.w)));
    float xmax = lane63(wave_max_chain(__builtin_fmaxf(__builtin_fmaxf(u.x, u.y),
                                                       __builtin_fmaxf(u.z, u.w))));
    float xmin = lane63(wave_min_chain(__builtin_fminf(__builtin_fminf(u.x, u.y),
                                                       __builtin_fminf(u.z, u.w))));

    float var = (qsum - ssum * ssum * (1.0f / DD)) * (1.0f / (DD - 1)); // ddof=1
    float bw = 0.9f * __builtin_sqrtf(var) * 0.32987697769322355f;      // *256^-0.2
    float invbw = __builtin_amdgcn_rcpf(bw);
    v4f v = u * invbw;
    float meanv = ssum * invbw * (1.0f / DD);

    float L = (xmax - xmin) * invbw + 10.0f;   // periodization margin 10 sigma_k
    float invL = __builtin_amdgcn_rcpf(L);

    // v_sin/v_cos take revolutions; angle_1 = v/L revolutions (verified R7).
    v4f ph = v * invL;
    v4f s1, c1;
    s1.x = __builtin_amdgcn_sinf(ph.x); s1.y = __builtin_amdgcn_sinf(ph.y);
    s1.z = __builtin_amdgcn_sinf(ph.z); s1.w = __builtin_amdgcn_sinf(ph.w);
    c1.x = __builtin_amdgcn_cosf(ph.x); c1.y = __builtin_amdgcn_cosf(ph.y);
    c1.z = __builtin_amdgcn_cosf(ph.z); c1.w = __builtin_amdgcn_cosf(ph.w);
    v4f twoC = c1 + c1;   // Chebyshev multiplier 2*cos(theta)

    // gamma_m = e^{-m^2 w1^2 / 2} via multiplicative recurrence (exp2 folded).
    float w1sq = 39.4784176044f * invL * invL;  // (2pi/L)^2
    float g    = __builtin_amdgcn_exp2f(-0.72134752f * w1sq);
    float rr   = __builtin_amdgcn_exp2f(-2.16404256f * w1sq);
    const float rho = __builtin_amdgcn_exp2f(-1.44269504f * w1sq);

    float pc[MG], ps[MG];        // per-lane scaled partials (VGPR)
    float coefC[MG], coefS[MG];  // wave-uniform reduced coeffs (SGPR)
    v4f sA = s1, cA = c1; v4f sA1 = {0.f, 0.f, 0.f, 0.f}, cA1 = {1.f, 1.f, 1.f, 1.f};
    v4f sB = s1, cB = c1; v4f sB1 = {0.f, 0.f, 0.f, 0.f}, cB1 = {1.f, 1.f, 1.f, 1.f};
    v4f R0 = {0.f, 0.f, 0.f, 0.f}, R1 = {0.f, 0.f, 0.f, 0.f};

    // Prologue: group 0 partials + reduction.
    #pragma unroll
    for (int k = 0; k < MG; ++k) P1_ADV(k + 1, k);
    REDUCE_GRP();

    // Pipelined groups: P1(grp) jammed with P3(grp-1) per mode (independent
    // A/B chains interleaved at instruction granularity), then reduce grp.
    #pragma unroll
    for (int grp = 1; grp < MFIX / MG; ++grp) {
        #pragma unroll
        for (int k = 0; k < MG; ++k) {
            P1_ADV(grp * MG + k + 1, k);
            P3_ADV(k);
        }
        REDUCE_GRP();
    }

    // Epilogue group: P3(last).
    #pragma unroll
    for (int k = 0; k < MG; ++k) P3_ADV(k);

    v4f R = R0 + R1;

    // ---- Epilogue: y = (v-meanv)*2/L + R  (2/256 already folded into R)
    const float t2iL = invL + invL;
    v4f o;
    o.x = __builtin_fmaf(ppf_from_y(__builtin_fmaf(v.x - meanv, t2iL, R.x)), wv.x, bv.x);
    o.y = __builtin_fmaf(ppf_from_y(__builtin_fmaf(v.y - meanv, t2iL, R.y)), wv.y, bv.y);
    o.z = __builtin_fmaf(ppf_from_y(__builtin_fmaf(v.z - meanv, t2iL, R.z)), wv.z, bv.z);
    o.w = __builtin_fmaf(ppf_from_y(__builtin_fmaf(v.w - meanv, t2iL, R.w)), wv.w, bv.w);
    ((v4f*)(out + (size_t)row * DD))[lane] = o;
}

extern "C" void kernel_launch(void* const* d_in, const int* in_sizes, int n_in,
                              void* d_out, int out_size, void* d_ws, size_t ws_size,
                              hipStream_t stream) {
    const float* x = (const float*)d_in[0];
    const float* w = (const float*)d_in[1];
    const float* b = (const float*)d_in[2];
    float* out = (float*)d_out;
    const int nrows = in_sizes[0] / DD;
    kd_layernorm_kernel<<<nrows / NW, 64 * NW, 0, stream>>>(x, w, b, out);
}

// Round 5
// 66.930 us; speedup vs baseline: 1.6947x; 1.0097x over previous
//
#include <hip/hip_runtime.h>
#include <math.h>

#define DD 256
#define NW 4     // rows (waves) per block, 1 wave per row, 4 elems/lane
#define MFIX 24  // fixed mode count; with L = range_v+10, omega_24 >= 4.3 always
#define MG 8     // modes per pipeline group (3 groups of 8)

typedef float v2f __attribute__((ext_vector_type(2)));
typedef float v4f __attribute__((ext_vector_type(4)));

#define SPL2(c) ((v2f){(c), (c)})

// ---- DPP wave-64 reduction helpers (no LDS, no barrier) ----
template <int CTRL>
__device__ __forceinline__ float dpp_add(float x) {
    return x + __int_as_float(__builtin_amdgcn_update_dpp(
        0, __float_as_int(x), CTRL, 0xf, 0xf, false));
}
template <int CTRL>
__device__ __forceinline__ float dpp_mov_self(float x) {
    return __int_as_float(__builtin_amdgcn_update_dpp(
        __float_as_int(x), __float_as_int(x), CTRL, 0xf, 0xf, false));
}
// After this chain lane 63 holds the 64-lane total (other lanes partial).
__device__ __forceinline__ float wave_sum_chain(float x) {
    x = dpp_add<0x111>(x); x = dpp_add<0x112>(x);
    x = dpp_add<0x114>(x); x = dpp_add<0x118>(x);
    x = dpp_add<0x142>(x); x = dpp_add<0x143>(x);
    return x;
}
__device__ __forceinline__ float lane63(float x) {
    return __int_as_float(__builtin_amdgcn_readlane(__float_as_int(x), 63));
}
__device__ __forceinline__ float wave_max_chain(float x) {
    x = __builtin_fmaxf(x, dpp_mov_self<0x111>(x));
    x = __builtin_fmaxf(x, dpp_mov_self<0x112>(x));
    x = __builtin_fmaxf(x, dpp_mov_self<0x114>(x));
    x = __builtin_fmaxf(x, dpp_mov_self<0x118>(x));
    x = __builtin_fmaxf(x, dpp_mov_self<0x142>(x));
    x = __builtin_fmaxf(x, dpp_mov_self<0x143>(x));
    return x;
}
__device__ __forceinline__ float wave_min_chain(float x) {
    x = __builtin_fminf(x, dpp_mov_self<0x111>(x));
    x = __builtin_fminf(x, dpp_mov_self<0x112>(x));
    x = __builtin_fminf(x, dpp_mov_self<0x114>(x));
    x = __builtin_fminf(x, dpp_mov_self<0x118>(x));
    x = __builtin_fminf(x, dpp_mov_self<0x142>(x));
    x = __builtin_fminf(x, dpp_mov_self<0x143>(x));
    return x;
}

// Giles' erfinv, central branch (|y| <= 1-1/256 => w <= 4.86 < 5), branchless.
// Packed-pair form: elementwise ops pattern-match to v_pk_fma_f32/v_pk_mul_f32
// (VOP3P), halving issue count vs scalar; per-element numerics identical.
__device__ __forceinline__ v2f ppf2(v2f y) {
    v2f omy2 = __builtin_elementwise_fma(-y, y, SPL2(1.0f));
    v2f lg;
    lg.x = __builtin_amdgcn_logf(omy2.x);
    lg.y = __builtin_amdgcn_logf(omy2.y);
    v2f wg = __builtin_elementwise_fma(-lg, SPL2(0.69314718056f), SPL2(-2.5f));
    v2f p = SPL2(2.81022636e-08f);
    p = __builtin_elementwise_fma(p, wg, SPL2(3.43273939e-07f));
    p = __builtin_elementwise_fma(p, wg, SPL2(-3.5233877e-06f));
    p = __builtin_elementwise_fma(p, wg, SPL2(-4.39150654e-06f));
    p = __builtin_elementwise_fma(p, wg, SPL2(0.00021858087f));
    p = __builtin_elementwise_fma(p, wg, SPL2(-0.00125372503f));
    p = __builtin_elementwise_fma(p, wg, SPL2(-0.00417768164f));
    p = __builtin_elementwise_fma(p, wg, SPL2(0.246640727f));
    p = __builtin_elementwise_fma(p, wg, SPL2(1.50140941f));
    return p * y * SPL2(1.41421356237309505f);
}

// P1: scaled Fourier partials for one mode from state A, advance A (Chebyshev
// 3-term, packed pairs: 4 v_pk_fma_f32 per mode instead of 8 scalar v_fma).
// Scale folded: sc_m = gamma_m / (128*pi*m) [includes epilogue's 2/256];
// sine partial pre-negated so P3 is a plain FMA.
#define P1_ADV(MODE, K) do {                                                  \
    const float sc_ = g * (0.0024867959f / (float)(MODE));                    \
    pc[K] = ((cAl.x + cAl.y) + (cAh.x + cAh.y)) * sc_;                        \
    ps[K] = ((sAl.x + sAl.y) + (sAh.x + sAh.y)) * (-sc_);                     \
    g *= rr; rr *= rho;                                                       \
    v2f snl_ = __builtin_elementwise_fma(twoCl, sAl, -sA1l);                  \
    v2f snh_ = __builtin_elementwise_fma(twoCh, sAh, -sA1h);                  \
    v2f cnl_ = __builtin_elementwise_fma(twoCl, cAl, -cA1l);                  \
    v2f cnh_ = __builtin_elementwise_fma(twoCh, cAh, -cA1h);                  \
    sA1l = sAl; sA1h = sAh; sAl = snl_; sAh = snh_;                           \
    cA1l = cAl; cA1h = cAh; cAl = cnl_; cAh = cnh_;                           \
} while (0)

// P3: R += coefC*sin(m t) + coefS*cos(m t) (coefS pre-negated), advance B.
// 8 v_pk_fma_f32 per mode (4 accum on split accumulators + 4 recurrence).
#define P3_ADV(K) do {                                                        \
    v2f cc_ = SPL2(coefC[K]);                                                 \
    v2f ss_ = SPL2(coefS[K]);                                                 \
    R0l = __builtin_elementwise_fma(sBl, cc_, R0l);                           \
    R0h = __builtin_elementwise_fma(sBh, cc_, R0h);                           \
    R1l = __builtin_elementwise_fma(cBl, ss_, R1l);                           \
    R1h = __builtin_elementwise_fma(cBh, ss_, R1h);                           \
    v2f snl_ = __builtin_elementwise_fma(twoCl, sBl, -sB1l);                  \
    v2f snh_ = __builtin_elementwise_fma(twoCh, sBh, -sB1h);                  \
    v2f cnl_ = __builtin_elementwise_fma(twoCl, cBl, -cB1l);                  \
    v2f cnh_ = __builtin_elementwise_fma(twoCh, cBh, -cB1h);                  \
    sB1l = sBl; sB1h = sBh; sBl = snl_; sBh = snh_;                           \
    cB1l = cBl; cB1h = cBh; cBl = cnl_; cBh = cnh_;                           \
} while (0)

// 2*MG independent DPP reduction chains -> wave-uniform coeffs; readlane
// pins them to SGPRs. (DPP is 32-bit only -- not packable.)
#define REDUCE_GRP() do {                                                     \
    _Pragma("unroll")                                                         \
    for (int k_ = 0; k_ < MG; ++k_) {                                         \
        coefC[k_] = lane63(wave_sum_chain(pc[k_]));                           \
        coefS[k_] = lane63(wave_sum_chain(ps[k_]));                           \
    }                                                                         \
} while (0)

// Poisson-summation KDE-CDF, group-pipelined, 1 wave per row (no LDS/barriers),
// all elementwise math in packed-f32 pairs (VOP3P). Occupancy is grid-capped
// at 4 waves/SIMD (4096 waves / 1024 SIMDs), so issue count is the lever.
// NO launch_bounds min-waves arg: that caps VGPRs at ~256/min_waves and was
// the R1/R2 scratch-spill cause.
__global__ __launch_bounds__(64 * NW) void kd_layernorm_kernel(
        const float* __restrict__ x,
        const float* __restrict__ wgt,
        const float* __restrict__ bia,
        float* __restrict__ out) {
    const int lane = threadIdx.x & 63;
    const int wid  = threadIdx.x >> 6;
    const int row  = blockIdx.x * NW + wid;

    const v4f u = ((const v4f*)(x + (size_t)row * DD))[lane];
    // weight/bias: tiny, L2-resident; issue early, consumed only in epilogue.
    const v4f wv4 = ((const v4f*)wgt)[lane];
    const v4f bv4 = ((const v4f*)bia)[lane];

    // Stats preamble: exact same scalar ops/association as validated rounds.
    float ssum = lane63(wave_sum_chain((u.x + u.y) + (u.z + u.w)));
    float qsum = lane63(wave_sum_chain(__builtin_fmaf(u.x, u.x, u.y * u.y) +
                                       __builtin_fmaf(u.z, u.z, u.w * u.w)));
    float xmax = lane63(wave_max_chain(__builtin_fmaxf(__builtin_fmaxf(u.x, u.y),
                                                       __builtin_fmaxf(u.z, u.w))));
    float xmin = lane63(wave_min_chain(__builtin_fminf(__builtin_fminf(u.x, u.y),
                                                       __builtin_fminf(u.z, u.w))));

    float var = (qsum - ssum * ssum * (1.0f / DD)) * (1.0f / (DD - 1)); // ddof=1
    float bw = 0.9f * __builtin_sqrtf(var) * 0.32987697769322355f;      // *256^-0.2
    float invbw = __builtin_amdgcn_rcpf(bw);
    v2f vl = ((v2f){u.x, u.y}) * invbw;
    v2f vh = ((v2f){u.z, u.w}) * invbw;
    float meanv = ssum * invbw * (1.0f / DD);

    float L = (xmax - xmin) * invbw + 10.0f;   // periodization margin 10 sigma_k
    float invL = __builtin_amdgcn_rcpf(L);

    // v_sin/v_cos take revolutions; angle_1 = v/L revolutions (verified R7).
    v2f phl = vl * invL, phh = vh * invL;
    v2f s1l, s1h, c1l, c1h;
    s1l.x = __builtin_amdgcn_sinf(phl.x); s1l.y = __builtin_amdgcn_sinf(phl.y);
    s1h.x = __builtin_amdgcn_sinf(phh.x); s1h.y = __builtin_amdgcn_sinf(phh.y);
    c1l.x = __builtin_amdgcn_cosf(phl.x); c1l.y = __builtin_amdgcn_cosf(phl.y);
    c1h.x = __builtin_amdgcn_cosf(phh.x); c1h.y = __builtin_amdgcn_cosf(phh.y);
    v2f twoCl = c1l + c1l, twoCh = c1h + c1h;   // Chebyshev multiplier 2cos

    // gamma_m = e^{-m^2 w1^2 / 2} via multiplicative recurrence (exp2 folded).
    float w1sq = 39.4784176044f * invL * invL;  // (2pi/L)^2
    float g    = __builtin_amdgcn_exp2f(-0.72134752f * w1sq);
    float rr   = __builtin_amdgcn_exp2f(-2.16404256f * w1sq);
    const float rho = __builtin_amdgcn_exp2f(-1.44269504f * w1sq);

    float pc[MG], ps[MG];        // per-lane scaled partials (VGPR)
    float coefC[MG], coefS[MG];  // wave-uniform reduced coeffs (SGPR)
    v2f sAl = s1l, sAh = s1h, cAl = c1l, cAh = c1h;
    v2f sA1l = SPL2(0.f), sA1h = SPL2(0.f), cA1l = SPL2(1.f), cA1h = SPL2(1.f);
    v2f sBl = s1l, sBh = s1h, cBl = c1l, cBh = c1h;
    v2f sB1l = SPL2(0.f), sB1h = SPL2(0.f), cB1l = SPL2(1.f), cB1h = SPL2(1.f);
    v2f R0l = SPL2(0.f), R0h = SPL2(0.f), R1l = SPL2(0.f), R1h = SPL2(0.f);

    // Prologue: group 0 partials + reduction.
    #pragma unroll
    for (int k = 0; k < MG; ++k) P1_ADV(k + 1, k);
    REDUCE_GRP();

    // Pipelined groups: P1(grp) jammed with P3(grp-1) per mode (independent
    // A/B chains interleaved at instruction granularity), then reduce grp.
    #pragma unroll
    for (int grp = 1; grp < MFIX / MG; ++grp) {
        #pragma unroll
        for (int k = 0; k < MG; ++k) {
            P1_ADV(grp * MG + k + 1, k);
            P3_ADV(k);
        }
        REDUCE_GRP();
    }

    // Epilogue group: P3(last).
    #pragma unroll
    for (int k = 0; k < MG; ++k) P3_ADV(k);

    v2f Rl = R0l + R1l, Rh = R0h + R1h;

    // ---- Epilogue: y = (v-meanv)*2/L + R  (2/256 already folded into R)
    const float t2iL = invL + invL;
    v2f yl = __builtin_elementwise_fma(vl - SPL2(meanv), SPL2(t2iL), Rl);
    v2f yh = __builtin_elementwise_fma(vh - SPL2(meanv), SPL2(t2iL), Rh);
    v2f zl = ppf2(yl), zh = ppf2(yh);
    v2f ol = __builtin_elementwise_fma(zl, (v2f){wv4.x, wv4.y}, (v2f){bv4.x, bv4.y});
    v2f oh = __builtin_elementwise_fma(zh, (v2f){wv4.z, wv4.w}, (v2f){bv4.z, bv4.w});
    v4f o4 = {ol.x, ol.y, oh.x, oh.y};
    ((v4f*)(out + (size_t)row * DD))[lane] = o4;
}

extern "C" void kernel_launch(void* const* d_in, const int* in_sizes, int n_in,
                              void* d_out, int out_size, void* d_ws, size_t ws_size,
                              hipStream_t stream) {
    const float* x = (const float*)d_in[0];
    const float* w = (const float*)d_in[1];
    const float* b = (const float*)d_in[2];
    float* out = (float*)d_out;
    const int nrows = in_sizes[0] / DD;
    kd_layernorm_kernel<<<nrows / NW, 64 * NW, 0, stream>>>(x, w, b, out);
}